// Round 1
// baseline (1909.788 us; speedup 1.0000x reference)
//
#include <hip/hip_runtime.h>

// GAT_14147622273466: out[m,:] = x[m,:] @ Wl^T + (sum_k wa[k]*neigh[m,k,:]) @ Wr^T
// M = 64*4096 = 262144, D = 256, K = 5, OUT = 256. fp32 in/out, bf16 MFMA inside.

typedef short bf16x8 __attribute__((ext_vector_type(8)));
typedef float f32x4 __attribute__((ext_vector_type(4)));

#define M_TOT 262144
#define D_ 256
#define K_ 5
#define O_ 256
#define KTOT 512   // concat [x | aggr]
#define MT 64      // rows per workgroup

__device__ __forceinline__ unsigned short f2bf(float f) {
    union { float f; unsigned u; } a; a.f = f;
    unsigned r = a.u + 0x7fffu + ((a.u >> 16) & 1u);   // round-nearest-even
    return (unsigned short)(r >> 16);
}

// Pre-swizzle W_cat = [Wl | Wr] (fp32 [256][512] logical) into MFMA-B fragment
// order, bf16: frag f = ot*16 + kt (ot: 16 out-tiles of 16, kt: 16 k-tiles of 32).
// Lane l of frag holds B[k][n] with n = l&15, k = kt*32 + (l>>4)*8 + j, j=0..7,
// stored contiguously so a wave reads its frag as one coalesced dwordx4 stream.
__global__ void prep_b(const float* __restrict__ wl, const float* __restrict__ wr,
                       unsigned short* __restrict__ Bfr) {
    int slot = blockIdx.x * 256 + threadIdx.x;   // 256 frags * 64 lanes = 16384 slots
    int l  = slot & 63;
    int f  = slot >> 6;
    int ot = f >> 4, kt = f & 15;
    int o  = ot * 16 + (l & 15);
    int kb = kt * 32 + (l >> 4) * 8;
    union { unsigned short s[8]; int4 v; } u;
#pragma unroll
    for (int j = 0; j < 8; ++j) {
        int k = kb + j;
        float val = (k < D_) ? wl[o * D_ + k] : wr[o * D_ + (k - D_)];
        u.s[j] = f2bf(val);
    }
    ((int4*)Bfr)[slot] = u.v;
}

__global__ __launch_bounds__(256, 2) void gat_fused(
    const float* __restrict__ x, const float* __restrict__ nx,
    const float* __restrict__ wa, const unsigned short* __restrict__ Bfr,
    float* __restrict__ out) {
    __shared__ short A[MT * KTOT];   // bf16 bits, row-major [64][512] = 64 KiB exactly
    const int tid = threadIdx.x;
    const long mbase = (long)blockIdx.x * MT;
    const float w0 = wa[0], w1 = wa[1], w2 = wa[2], w3 = wa[3], w4 = wa[4];

    // ---- stage A tile: x (coalesced float4) + fp32 aggregation -> bf16 LDS ----
#pragma unroll 2
    for (int i = 0; i < 16; ++i) {
        int idx = i * 256 + tid;      // 0..4095 (row, float4-chunk)
        int row = idx >> 6;           // 0..63
        int c4  = idx & 63;           // float4 index within 256-d row
        long m  = mbase + row;
        float4 xv = ((const float4*)(x + m * D_))[c4];
        const float4* npt = (const float4*)(nx + m * (long)(K_ * D_));
        float4 n0 = npt[c4];
        float4 n1 = npt[64 + c4];
        float4 n2 = npt[128 + c4];
        float4 n3 = npt[192 + c4];
        float4 n4 = npt[256 + c4];
        float4 ag;
        ag.x = w0*n0.x + w1*n1.x + w2*n2.x + w3*n3.x + w4*n4.x;
        ag.y = w0*n0.y + w1*n1.y + w2*n2.y + w3*n3.y + w4*n4.y;
        ag.z = w0*n0.z + w1*n1.z + w2*n2.z + w3*n3.z + w4*n4.z;
        ag.w = w0*n0.w + w1*n1.w + w2*n2.w + w3*n3.w + w4*n4.w;
        union { unsigned short s[4]; int2 v; } px, pa;
        px.s[0] = f2bf(xv.x); px.s[1] = f2bf(xv.y); px.s[2] = f2bf(xv.z); px.s[3] = f2bf(xv.w);
        pa.s[0] = f2bf(ag.x); pa.s[1] = f2bf(ag.y); pa.s[2] = f2bf(ag.z); pa.s[3] = f2bf(ag.w);
        *(int2*)&A[row * KTOT + c4 * 4]      = px.v;
        *(int2*)&A[row * KTOT + D_ + c4 * 4] = pa.v;
    }
    __syncthreads();

    // ---- MFMA: 64 rows x 256 outs; wave w owns out cols [64w, 64w+64) ----
    const int wave = tid >> 6;
    const int lane = tid & 63;
    const int lr = lane & 15;    // A row-in-tile / B out-col-in-tile
    const int lh = lane >> 4;    // k-octet selector

    f32x4 acc[4][4];
#pragma unroll
    for (int mi = 0; mi < 4; ++mi)
#pragma unroll
        for (int oi = 0; oi < 4; ++oi)
            acc[mi][oi] = (f32x4){0.f, 0.f, 0.f, 0.f};

    const int4* bp = (const int4*)Bfr;
    for (int kt = 0; kt < 16; ++kt) {
        bf16x8 bfr[4];
#pragma unroll
        for (int oi = 0; oi < 4; ++oi) {
            int f = (wave * 4 + oi) * 16 + kt;
            int4 t = bp[f * 64 + lane];          // coalesced 16B/lane from L2
            bfr[oi] = __builtin_bit_cast(bf16x8, t);
        }
        bf16x8 af[4];
#pragma unroll
        for (int mi = 0; mi < 4; ++mi)
            af[mi] = *(const bf16x8*)&A[(mi * 16 + lr) * KTOT + kt * 32 + lh * 8];
#pragma unroll
        for (int mi = 0; mi < 4; ++mi)
#pragma unroll
            for (int oi = 0; oi < 4; ++oi)
                acc[mi][oi] = __builtin_amdgcn_mfma_f32_16x16x32_bf16(
                    af[mi], bfr[oi], acc[mi][oi], 0, 0, 0);
    }

    // ---- epilogue: C/D layout col=lane&15, row=(lane>>4)*4+reg ----
#pragma unroll
    for (int mi = 0; mi < 4; ++mi) {
#pragma unroll
        for (int r = 0; r < 4; ++r) {
            long m = mbase + mi * 16 + lh * 4 + r;
            float* op = out + m * O_ + wave * 64 + lr;
#pragma unroll
            for (int oi = 0; oi < 4; ++oi)
                op[oi * 16] = acc[mi][oi][r];
        }
    }
}

extern "C" void kernel_launch(void* const* d_in, const int* in_sizes, int n_in,
                              void* d_out, int out_size, void* d_ws, size_t ws_size,
                              hipStream_t stream) {
    const float* x  = (const float*)d_in[0];
    const float* nx = (const float*)d_in[1];
    const float* wa = (const float*)d_in[2];
    const float* wl = (const float*)d_in[3];
    const float* wr = (const float*)d_in[4];
    float* out = (float*)d_out;
    unsigned short* Bfr = (unsigned short*)d_ws;   // 256 KiB fragment-ordered bf16 weights

    prep_b<<<64, 256, 0, stream>>>(wl, wr, Bfr);           // rebuild every call (ws is re-poisoned)
    gat_fused<<<M_TOT / MT, 256, 0, stream>>>(x, nx, wa, Bfr, out);
}